// Round 1
// baseline (645.927 us; speedup 1.0000x reference)
//
#include <hip/hip_runtime.h>
#include <cstdint>
#include <cstddef>

#define THRESH   0.5f
#define NEGPOS   3
#define VAR0     0.1f
#define VAR1     0.2f
#define MAXO     64
#define NPRI     8
#define A1_T     256
#define FUSED_T  1024
#define FWAVES   (FUSED_T / 64)
#define MAXCH    16            // supports P <= FUSED_T*MAXCH = 16384 (P = 16320)

// ---------------------------------------------------------------------------
// Kernel A1: per-(batch, prior-chunk) matching. UNCHANGED (verified).
//  - per-prior best truth (strict > keeps first o == jnp.argmax axis=0),
//    emitted as code u8 = (best_ov >= THRESH) ? idx+1 : 0
//  - per-truth best prior via u64 key (iou_bits<<32 | ~p): atomicMax picks
//    max iou, ties -> smallest p (== jnp.argmax axis=1 first-occurrence).
// ---------------------------------------------------------------------------
__global__ __launch_bounds__(A1_T)
void match_kernel(const float* __restrict__ priors,
                  const float* __restrict__ targets,
                  unsigned char* __restrict__ code,
                  unsigned long long* __restrict__ g_bp,
                  int B, int P, int O, int chunks) {
    __shared__ float tx1[MAXO], ty1[MAXO], tx2[MAXO], ty2[MAXO], tarea[MAXO];
    const int b   = blockIdx.x / chunks;
    const int ch  = blockIdx.x % chunks;
    const int tid = threadIdx.x;

    if (tid < O) {
        const float* tr = targets + (size_t)(b * O + tid) * 5;
        float x1 = tr[0], y1 = tr[1], x2 = tr[2], y2 = tr[3];
        tx1[tid] = x1; ty1[tid] = y1; tx2[tid] = x2; ty2[tid] = y2;
        tarea[tid] = (x2 - x1) * (y2 - y1);
    }
    __syncthreads();

    float px1[NPRI], py1[NPRI], px2[NPRI], py2[NPRI], pa[NPRI], pov[NPRI];
    int   pidx[NPRI];
    const int p0 = ch * (A1_T * NPRI) + tid;
#pragma unroll
    for (int i = 0; i < NPRI; ++i) {
        int p = p0 + i * A1_T;
        pov[i] = -1.0f; pidx[i] = 0;
        px1[i] = 0.f; py1[i] = 0.f; px2[i] = 0.f; py2[i] = 0.f; pa[i] = 1.0f;
        if (p < P) {
            float4 pr = *(const float4*)(priors + (size_t)p * 4);
            px1[i] = pr.x - pr.z * 0.5f; py1[i] = pr.y - pr.w * 0.5f;
            px2[i] = pr.x + pr.z * 0.5f; py2[i] = pr.y + pr.w * 0.5f;
            pa[i]  = pr.z * pr.w;
        }
    }

    const int lane = tid & 63;
    for (int o = 0; o < O; ++o) {
        float ax1 = tx1[o], ay1 = ty1[o], ax2 = tx2[o], ay2 = ty2[o], aa = tarea[o];
        float bo = -1.0f; unsigned bp = 0u;
#pragma unroll
        for (int i = 0; i < NPRI; ++i) {
            float lx = fmaxf(ax1, px1[i]), ly = fmaxf(ay1, py1[i]);
            float rx = fminf(ax2, px2[i]), ry = fminf(ay2, py2[i]);
            float w = fmaxf(rx - lx, 0.0f), h = fmaxf(ry - ly, 0.0f);
            float inter = w * h;
            float iou = __fdividef(inter, aa + pa[i] - inter);
            if (iou > pov[i]) { pov[i] = iou; pidx[i] = o; }      // first o wins
            if (iou > bo)     { bo = iou; bp = (unsigned)(p0 + i * A1_T); }
        }
        unsigned long long key =
            ((unsigned long long)__float_as_uint(bo) << 32) |
            (unsigned long long)(0xFFFFFFFFu - bp);
#pragma unroll
        for (int d = 1; d < 64; d <<= 1) {
            unsigned long long other = __shfl_xor(key, d, 64);
            if (other > key) key = other;
        }
        if (lane == 0)
            atomicMax(&g_bp[(size_t)b * O + o], key);
    }

#pragma unroll
    for (int i = 0; i < NPRI; ++i) {
        int p = p0 + i * A1_T;
        if (p < P)
            code[(size_t)b * P + p] =
                (pov[i] >= THRESH) ? (unsigned char)(pidx[i] + 1) : (unsigned char)0;
    }
}

// ---------------------------------------------------------------------------
// Kernel A2: forced-match patch, PARALLELIZED. Serial "last truth wins on
// duplicate best_prior_idx" == only the largest o with a given prior writes.
// One block per batch, thread o checks o' > o for duplicates in LDS (O^2/64
// work, trivial). Replaces 64 threads x 50 serial dependent global loads.
// ---------------------------------------------------------------------------
__global__ __launch_bounds__(64)
void force_kernel(const unsigned long long* __restrict__ g_bp,
                  unsigned char* __restrict__ code,
                  int B, int P, int O) {
    const int b = blockIdx.x;
    const int o = threadIdx.x;
    __shared__ unsigned sp[MAXO];
    if (o < O)
        sp[o] = 0xFFFFFFFFu - (unsigned)(g_bp[(size_t)b * O + o] & 0xFFFFFFFFull);
    __syncthreads();
    if (o < O) {
        unsigned p = sp[o];
        bool win = true;
        for (int o2 = o + 1; o2 < O; ++o2)
            if (sp[o2] == p) { win = false; break; }
        if (win)
            code[(size_t)b * P + p] = (unsigned char)(o + 1);
    }
}

// ---------------------------------------------------------------------------
// Kernel B (fully fused per row): ce_pos + hard-negative mining, one block
// per (batch) row, 1024 threads.
//   - Each thread owns 16 priors (p = i*1024+tid); mce for the whole row
//     lives ENTIRELY IN REGISTERS (16 VGPR/thread) -- never touches memory.
//     (Was: 4.2 MB HBM write + ~5 re-reads by a separate mine kernel.)
//   - negatives: mce = LSE2(obj) - obj0  (== ce_c == ce_o, mined once)
//   - positives: wave-cooperative conf-row exp-sum (coalesced), butterfly
//     reduce, deposit S to owner lane; epilogue (ce_c, ce_o, smooth-L1).
//   - mining: 4-pass radix select over the register-resident row. Histogram
//     = per-wave private LDS copy (16 copies, no cross-wave atomics).
//     Bin scan is WAVE-PARALLEL: 256 bins folded 4-per-lane, descending
//     inclusive prefix via 6x shfl_up (was: tid0 serial 256x8x4 walk).
//   - one block per row => rowacc written with plain stores, no atomics.
//     top-k sum == sum(v > v_k) + (k - cnt_gt) * v_k; same sum feeds
//     loss_c and loss_obj. Phantom lanes (p >= P) carry r = 0.0f: they can
//     only land in bin 0 with value-bits 0, where vk == 0.0 makes their
//     count contribution vanish (same argument as positives' zeros).
// ---------------------------------------------------------------------------
__global__ __launch_bounds__(FUSED_T)
void fused_kernel(const float* __restrict__ loc, const float* __restrict__ conf,
                  const float* __restrict__ obj, const float* __restrict__ priors,
                  const float* __restrict__ targets,
                  const unsigned char* __restrict__ code,
                  float* __restrict__ rowacc,
                  int B, int P, int C, int O) {
    const int b = blockIdx.x;
    const int tid = threadIdx.x, wv = tid >> 6, lane = tid & 63;

    float r[MAXCH];                     // register-resident mce row slice
    float sl = 0.f, cec = 0.f, ceo = 0.f;
    int cntp = 0;                       // wave-uniform positive count

#pragma unroll
    for (int i = 0; i < MAXCH; ++i) {
        const int p = i * FUSED_T + tid;
        const unsigned t = (unsigned)(b * P + p);
        bool pos = false;
        unsigned cc = 0;
        float oby = 0.f, lse2 = 0.f;
        r[i] = 0.f;
        if (p < P) {
            cc = code[t];
            float2 ob = *(const float2*)(obj + (size_t)t * 2);
            float m = fmaxf(ob.x, ob.y);
            lse2 = m + __logf(__expf(ob.x - m) + __expf(ob.y - m));
            oby = ob.y;
            if (cc == 0) r[i] = lse2 - ob.x;     // negative: ce_c == ce_o
            else         pos = true;             // positive: r stays 0 for mining
        }

        const unsigned long long msk = __ballot(pos);
        cntp += __popcll(msk);

        // wave-cooperative conf-row exp-sum for each positive lane
        float myS = 0.f;
        unsigned long long remb = msk;
        while (remb) {
            const int src = __ffsll(remb) - 1;
            remb &= remb - 1;
            const unsigned t_s = (unsigned)__shfl((int)t, src, 64);
            const float* cr = conf + (size_t)t_s * C;
            float s = 0.f;
            for (int j = lane; j < C; j += 64) s += __expf(cr[j]);
#pragma unroll
            for (int d = 1; d < 64; d <<= 1) s += __shfl_xor(s, d, 64);
            if (lane == src) myS = s;
        }

        // parallel epilogue on positive lanes
        if (pos) {
            const float* cr = conf + (size_t)t * C;
            const float* tr = targets + (size_t)((unsigned)(b * O) + cc - 1u) * 5;
            float4 pr = *(const float4*)(priors + (size_t)p * 4);
            float4 ld = *(const float4*)(loc + (size_t)t * 4);
            float mx1 = tr[0], my1 = tr[1], mx2 = tr[2], my2 = tr[3];
            int   lbl = (int)tr[4];

            float lsec = __logf(myS);
            cec += lsec + lse2 - oby - cr[lbl];
            ceo += lse2 - oby;

            float gx  = ((mx1 + mx2) * 0.5f - pr.x) / (VAR0 * pr.z);
            float gy  = ((my1 + my2) * 0.5f - pr.y) / (VAR0 * pr.w);
            float gw2 = __logf((mx2 - mx1) / pr.z) / VAR1;
            float gh  = __logf((my2 - my1) / pr.w) / VAR1;
            float d0 = ld.x - gx,  a0 = fabsf(d0); sl += (a0 < 1.f) ? 0.5f * d0 * d0 : a0 - 0.5f;
            float d1 = ld.y - gy,  a1 = fabsf(d1); sl += (a1 < 1.f) ? 0.5f * d1 * d1 : a1 - 0.5f;
            float d2 = ld.z - gw2, a2 = fabsf(d2); sl += (a2 < 1.f) ? 0.5f * d2 * d2 : a2 - 0.5f;
            float d3 = ld.w - gh,  a3 = fabsf(d3); sl += (a3 < 1.f) ? 0.5f * d3 * d3 : a3 - 0.5f;
        }
    }

    // block reduction of positive-side partials -> direct stores (no atomics)
    __shared__ float red[FWAVES][4];
    __shared__ int s_npos;
#pragma unroll
    for (int d = 32; d > 0; d >>= 1) {
        sl  += __shfl_down(sl,  d, 64);
        cec += __shfl_down(cec, d, 64);
        ceo += __shfl_down(ceo, d, 64);
    }
    if (lane == 0) {
        red[wv][0] = (float)cntp; red[wv][1] = sl; red[wv][2] = cec; red[wv][3] = ceo;
    }
    __syncthreads();
    if (tid < 4) {
        float v = 0.f;
        for (int w = 0; w < FWAVES; ++w) v += red[w][tid];
        rowacc[(size_t)b * 16 + tid] = v;
        if (tid == 0) s_npos = (int)v;
    }
    __syncthreads();

    int k = NEGPOS * s_npos;
    if (k > P - 1) k = P - 1;
    if (k <= 0) {
        if (tid == 0) rowacc[(size_t)b * 16 + 4] = 0.f;
        return;
    }

    // ---- radix select over the register-resident row ----
    __shared__ unsigned hist[FWAVES][257];
    __shared__ unsigned binc[256];
    __shared__ unsigned s_prefix;
    __shared__ int      s_rem;

    unsigned prefix = 0u;
    int rem = k;
    for (int shift = 24; shift >= 0; shift -= 8) {
        for (int i = tid; i < FWAVES * 257; i += FUSED_T) (&hist[0][0])[i] = 0u;
        __syncthreads();
        const unsigned himask = (shift == 24) ? 0u : (0xFFFFFFFFu << (shift + 8));
#pragma unroll
        for (int i = 0; i < MAXCH; ++i) {
            unsigned bits = __float_as_uint(r[i]);
            if ((bits & himask) == prefix)
                atomicAdd(&hist[wv][(bits >> shift) & 0xFFu], 1u);
        }
        __syncthreads();
        if (tid < 256) {                 // fold the 16 wave-private copies
            unsigned c = 0;
            for (int h = 0; h < FWAVES; ++h) c += hist[h][tid];
            binc[tid] = c;
        }
        __syncthreads();
        if (tid < 64) {                  // wave-parallel descending bin scan
            const int bb0 = 255 - 4 * tid;
            unsigned c0 = binc[bb0], c1 = binc[bb0 - 1],
                     c2 = binc[bb0 - 2], c3 = binc[bb0 - 3];
            unsigned t4 = c0 + c1 + c2 + c3;
            unsigned incl = t4;
#pragma unroll
            for (int d = 1; d < 64; d <<= 1) {
                unsigned v = __shfl_up(incl, d, 64);
                if (tid >= d) incl += v;
            }
            const unsigned excl = incl - t4;   // count in bins above my group
            if ((int)excl < rem && rem <= (int)incl) {   // exactly one lane
                unsigned cum = excl;
                int bin, nrem;
                if ((int)(cum + c0) >= rem)      { bin = bb0;     nrem = rem - (int)cum; }
                else { cum += c0;
                if ((int)(cum + c1) >= rem)      { bin = bb0 - 1; nrem = rem - (int)cum; }
                else { cum += c1;
                if ((int)(cum + c2) >= rem)      { bin = bb0 - 2; nrem = rem - (int)cum; }
                else { cum += c2;                  bin = bb0 - 3; nrem = rem - (int)cum; } } }
                s_prefix = prefix | ((unsigned)bin << shift);
                s_rem    = nrem;
            }
        }
        __syncthreads();
        prefix = s_prefix;
        rem    = s_rem;
    }

    const float vk = __uint_as_float(prefix);
    float s = 0.f; int cnt = 0;
#pragma unroll
    for (int i = 0; i < MAXCH; ++i) {
        float v = r[i];
        if (__float_as_uint(v) > prefix) { s += v; ++cnt; }
    }
#pragma unroll
    for (int d = 32; d > 0; d >>= 1) {
        s   += __shfl_down(s, d, 64);
        cnt += __shfl_down(cnt, d, 64);
    }
    __shared__ float s_ws[FWAVES];
    __shared__ int   s_wc[FWAVES];
    if (lane == 0) { s_ws[wv] = s; s_wc[wv] = cnt; }
    __syncthreads();
    if (tid == 0) {
        float st = 0.f; int ct = 0;
        for (int w = 0; w < FWAVES; ++w) { st += s_ws[w]; ct += s_wc[w]; }
        rowacc[(size_t)b * 16 + 4] = st + (float)(k - ct) * vk;
    }
}

// ---------------------------------------------------------------------------
// Kernel D: final combine + divide by N. One wave. Per-row mined-negative
// sums now arrive via rowacc[...,4] (g_neg eliminated).
// ---------------------------------------------------------------------------
__global__ __launch_bounds__(64)
void finish_kernel(const float* __restrict__ rowacc,
                   float* __restrict__ out, int B) {
    const int lane = threadIdx.x;
    float npos = 0.f, sl = 0.f, cec = 0.f, ceo = 0.f, neg = 0.f;
    for (int b = lane; b < B; b += 64) {
        const float* rb = rowacc + (size_t)b * 16;
        float4 v = *(const float4*)rb;
        npos += v.x; sl += v.y; cec += v.z; ceo += v.w; neg += rb[4];
    }
#pragma unroll
    for (int d = 32; d > 0; d >>= 1) {
        npos += __shfl_down(npos, d, 64);
        sl   += __shfl_down(sl,   d, 64);
        cec  += __shfl_down(cec,  d, 64);
        ceo  += __shfl_down(ceo,  d, 64);
        neg  += __shfl_down(neg,  d, 64);
    }
    if (lane == 0) {
        out[0] = sl / npos;
        out[1] = (cec + neg) / npos;
        out[2] = (ceo + neg) / npos;
    }
}

extern "C" void kernel_launch(void* const* d_in, const int* in_sizes, int n_in,
                              void* d_out, int out_size, void* d_ws, size_t ws_size,
                              hipStream_t stream) {
    const float* loc     = (const float*)d_in[0];
    const float* conf    = (const float*)d_in[1];
    const float* obj     = (const float*)d_in[2];
    const float* priors  = (const float*)d_in[3];
    const float* targets = (const float*)d_in[4];

    const int P = in_sizes[3] / 4;
    const int B = in_sizes[0] / (4 * P);
    const int C = in_sizes[1] / (B * P);
    const int O = in_sizes[4] / (5 * B);

    // workspace: [g_bp (zeroed) | rowacc | code]   (mce + g_neg eliminated)
    char* ws = (char*)d_ws;
    size_t off = 0;
    unsigned long long* g_bp = (unsigned long long*)(ws + off);
    off += (size_t)B * O * sizeof(unsigned long long);
    const size_t zero_bytes = off;                 // only g_bp needs zeroing
    float* rowacc = (float*)(ws + off);            off += (size_t)B * 16 * sizeof(float);
    off = (off + 127) & ~(size_t)127;
    unsigned char* code = (unsigned char*)(ws + off); off += (size_t)B * P;

    hipMemsetAsync(d_ws, 0, zero_bytes, stream);

    const int chunks = (P + A1_T * NPRI - 1) / (A1_T * NPRI);
    match_kernel<<<B * chunks, A1_T, 0, stream>>>(priors, targets, code, g_bp,
                                                  B, P, O, chunks);
    force_kernel<<<B, 64, 0, stream>>>(g_bp, code, B, P, O);
    fused_kernel<<<B, FUSED_T, 0, stream>>>(loc, conf, obj, priors, targets,
                                            code, rowacc, B, P, C, O);
    finish_kernel<<<1, 64, 0, stream>>>(rowacc, (float*)d_out, B);
}

// Round 4
// 511.196 us; speedup vs baseline: 1.2636x; 1.2636x over previous
//
#include <hip/hip_runtime.h>
#include <cstdint>
#include <cstddef>

#define THRESH   0.5f
#define NEGPOS   3
#define VAR0     0.1f
#define VAR1     0.2f
#define MAXO     64
#define NPRI     8
#define A1_T     256
#define MINE_T   1024
#define MINE_W   (MINE_T / 64)
#define MINE_CH  16            // supports P <= MINE_T*MINE_CH = 16384 (P = 16320)

// ---------------------------------------------------------------------------
// Kernel A1: per-(batch, prior-chunk) matching. UNCHANGED (verified).
//  - per-prior best truth (strict > keeps first o == jnp.argmax axis=0),
//    emitted as code u8 = (best_ov >= THRESH) ? idx+1 : 0
//  - per-truth best prior via u64 key (iou_bits<<32 | ~p): atomicMax picks
//    max iou, ties -> smallest p (== jnp.argmax axis=1 first-occurrence).
// ---------------------------------------------------------------------------
__global__ __launch_bounds__(A1_T)
void match_kernel(const float* __restrict__ priors,
                  const float* __restrict__ targets,
                  unsigned char* __restrict__ code,
                  unsigned long long* __restrict__ g_bp,
                  int B, int P, int O, int chunks) {
    __shared__ float tx1[MAXO], ty1[MAXO], tx2[MAXO], ty2[MAXO], tarea[MAXO];
    const int b   = blockIdx.x / chunks;
    const int ch  = blockIdx.x % chunks;
    const int tid = threadIdx.x;

    if (tid < O) {
        const float* tr = targets + (size_t)(b * O + tid) * 5;
        float x1 = tr[0], y1 = tr[1], x2 = tr[2], y2 = tr[3];
        tx1[tid] = x1; ty1[tid] = y1; tx2[tid] = x2; ty2[tid] = y2;
        tarea[tid] = (x2 - x1) * (y2 - y1);
    }
    __syncthreads();

    float px1[NPRI], py1[NPRI], px2[NPRI], py2[NPRI], pa[NPRI], pov[NPRI];
    int   pidx[NPRI];
    const int p0 = ch * (A1_T * NPRI) + tid;
#pragma unroll
    for (int i = 0; i < NPRI; ++i) {
        int p = p0 + i * A1_T;
        pov[i] = -1.0f; pidx[i] = 0;
        px1[i] = 0.f; py1[i] = 0.f; px2[i] = 0.f; py2[i] = 0.f; pa[i] = 1.0f;
        if (p < P) {
            float4 pr = *(const float4*)(priors + (size_t)p * 4);
            px1[i] = pr.x - pr.z * 0.5f; py1[i] = pr.y - pr.w * 0.5f;
            px2[i] = pr.x + pr.z * 0.5f; py2[i] = pr.y + pr.w * 0.5f;
            pa[i]  = pr.z * pr.w;
        }
    }

    const int lane = tid & 63;
    for (int o = 0; o < O; ++o) {
        float ax1 = tx1[o], ay1 = ty1[o], ax2 = tx2[o], ay2 = ty2[o], aa = tarea[o];
        float bo = -1.0f; unsigned bp = 0u;
#pragma unroll
        for (int i = 0; i < NPRI; ++i) {
            float lx = fmaxf(ax1, px1[i]), ly = fmaxf(ay1, py1[i]);
            float rx = fminf(ax2, px2[i]), ry = fminf(ay2, py2[i]);
            float w = fmaxf(rx - lx, 0.0f), h = fmaxf(ry - ly, 0.0f);
            float inter = w * h;
            float iou = __fdividef(inter, aa + pa[i] - inter);
            if (iou > pov[i]) { pov[i] = iou; pidx[i] = o; }      // first o wins
            if (iou > bo)     { bo = iou; bp = (unsigned)(p0 + i * A1_T); }
        }
        unsigned long long key =
            ((unsigned long long)__float_as_uint(bo) << 32) |
            (unsigned long long)(0xFFFFFFFFu - bp);
#pragma unroll
        for (int d = 1; d < 64; d <<= 1) {
            unsigned long long other = __shfl_xor(key, d, 64);
            if (other > key) key = other;
        }
        if (lane == 0)
            atomicMax(&g_bp[(size_t)b * O + o], key);
    }

#pragma unroll
    for (int i = 0; i < NPRI; ++i) {
        int p = p0 + i * A1_T;
        if (p < P)
            code[(size_t)b * P + p] =
                (pov[i] >= THRESH) ? (unsigned char)(pidx[i] + 1) : (unsigned char)0;
    }
}

// ---------------------------------------------------------------------------
// Kernel A2: forced-match patch, parallel (verified round 1). Serial "last
// truth wins on duplicate best_prior_idx" == only the largest o with a given
// prior writes. One block per batch; thread o checks o' > o in LDS.
// ---------------------------------------------------------------------------
__global__ __launch_bounds__(64)
void force_kernel(const unsigned long long* __restrict__ g_bp,
                  unsigned char* __restrict__ code,
                  int B, int P, int O) {
    const int b = blockIdx.x;
    const int o = threadIdx.x;
    __shared__ unsigned sp[MAXO];
    if (o < O)
        sp[o] = 0xFFFFFFFFu - (unsigned)(g_bp[(size_t)b * O + o] & 0xFFFFFFFFull);
    __syncthreads();
    if (o < O) {
        unsigned p = sp[o];
        bool win = true;
        for (int o2 = o + 1; o2 < O; ++o2)
            if (sp[o2] == p) { win = false; break; }
        if (win)
            code[(size_t)b * P + p] = (unsigned char)(o + 1);
    }
}

// ---------------------------------------------------------------------------
// Kernel B: streaming negative pass + wave-cooperative positives. UNCHANGED
// from the verified 587us version: 4096 blocks x 256 thr saturates all CUs
// (the round-1 fusion into 64 blocks cost 59us -- 25% CU utilization + VGPR
// cap at 1024 thr/block). Block-reduced partials -> 4 atomics/block.
// ---------------------------------------------------------------------------
__global__ __launch_bounds__(256)
void ce_pos_kernel(const float* __restrict__ loc, const float* __restrict__ conf,
                   const float* __restrict__ obj, const float* __restrict__ priors,
                   const float* __restrict__ targets,
                   const unsigned char* __restrict__ code,
                   float* __restrict__ mce, float* __restrict__ rowacc,
                   int B, int P, int C, int O) {
    const int b = blockIdx.y;
    const int p = blockIdx.x * 256 + threadIdx.x;
    const int tid = threadIdx.x, wv = tid >> 6, lane = tid & 63;

    bool pos = false;
    unsigned cc = 0;
    const unsigned t = (unsigned)(b * P + p);
    float obx = 0.f, oby = 0.f, lse2 = 0.f;
    if (p < P) {
        cc = code[t];
        float2 ob = *(const float2*)(obj + (size_t)t * 2);
        obx = ob.x; oby = ob.y;
        float m = fmaxf(obx, oby);
        lse2 = m + __logf(__expf(obx - m) + __expf(oby - m));
        if (cc == 0) {
            mce[t] = lse2 - obx;         // negative: ce_c == ce_o, mined once
        } else {
            mce[t] = 0.0f;               // positive: zeroed for mining
            pos = true;
        }
    }

    // wave-cooperative conf-row LSE for each positive lane
    const unsigned long long msk = __ballot(pos);
    float myS = 0.f;
    unsigned long long rem = msk;
    while (rem) {
        const int src = __ffsll(rem) - 1;
        rem &= rem - 1;
        const unsigned t_s = (unsigned)__shfl((int)t, src, 64);
        const float* cr = conf + (size_t)t_s * C;
        float s = 0.f;
        for (int j = lane; j < C; j += 64) s += __expf(cr[j]);
#pragma unroll
        for (int d = 1; d < 64; d <<= 1) s += __shfl_xor(s, d, 64);
        if (lane == src) myS = s;
    }

    // parallel epilogue on positive lanes
    float sl = 0.f, cec = 0.f, ceo = 0.f;
    if (pos) {
        const float* cr = conf + (size_t)t * C;
        const float* tr = targets + (size_t)((unsigned)(b * O) + cc - 1u) * 5;
        float4 pr = *(const float4*)(priors + (size_t)p * 4);
        float4 ld = *(const float4*)(loc + (size_t)t * 4);
        float mx1 = tr[0], my1 = tr[1], mx2 = tr[2], my2 = tr[3];
        int   lbl = (int)tr[4];

        float lsec = __logf(myS);
        cec = lsec + lse2 - oby - cr[lbl];
        ceo = lse2 - oby;

        float gx  = ((mx1 + mx2) * 0.5f - pr.x) / (VAR0 * pr.z);
        float gy  = ((my1 + my2) * 0.5f - pr.y) / (VAR0 * pr.w);
        float gw2 = __logf((mx2 - mx1) / pr.z) / VAR1;
        float gh  = __logf((my2 - my1) / pr.w) / VAR1;
        float d0 = ld.x - gx,  a0 = fabsf(d0); sl += (a0 < 1.f) ? 0.5f * d0 * d0 : a0 - 0.5f;
        float d1 = ld.y - gy,  a1 = fabsf(d1); sl += (a1 < 1.f) ? 0.5f * d1 * d1 : a1 - 0.5f;
        float d2 = ld.z - gw2, a2 = fabsf(d2); sl += (a2 < 1.f) ? 0.5f * d2 * d2 : a2 - 0.5f;
        float d3 = ld.w - gh,  a3 = fabsf(d3); sl += (a3 < 1.f) ? 0.5f * d3 * d3 : a3 - 0.5f;
    }

    // block reduction -> 4 atomics per block on this row's private 64B line
    float cntp = (float)__popcll(msk);   // wave-uniform; counted once per wave below
    __shared__ float red[4][4];
#pragma unroll
    for (int d = 32; d > 0; d >>= 1) {
        sl  += __shfl_down(sl,  d, 64);
        cec += __shfl_down(cec, d, 64);
        ceo += __shfl_down(ceo, d, 64);
    }
    if (lane == 0) {
        red[wv][0] = cntp; red[wv][1] = sl; red[wv][2] = cec; red[wv][3] = ceo;
    }
    __syncthreads();
    if (tid < 4) {
        float v = red[0][tid] + red[1][tid] + red[2][tid] + red[3][tid];
        if (v != 0.0f)
            atomicAdd(rowacc + (size_t)b * 16 + tid, v);
    }
}

// ---------------------------------------------------------------------------
// Kernel C: per-row radix-select top-k sum.
//  - row loaded ONCE into 16 regs/thread; 4 radix passes + final sum run
//    from registers (was: 5 streaming passes over mce).
//  - per-wave private histograms (16 copies); wave-parallel descending bin
//    scan: 4 bins/lane folded, 6x shfl_up inclusive prefix (was: tid0
//    serial 256x8x4 dependent-LDS walk).
//  Phantom lanes (p >= P) carry 0.0f: they can only be selected in bin 0
//  with vk == 0.0, where the (k - cnt) * vk correction vanishes.
//  top-k sum == sum(v > v_k) + (k - cnt_gt) * v_k; feeds loss_c and loss_obj.
// ---------------------------------------------------------------------------
__global__ __launch_bounds__(MINE_T)
void mine_kernel(const float* __restrict__ mce, const float* __restrict__ rowacc,
                 float* __restrict__ g_neg, int P) {
    const int b = blockIdx.x;
    const float* row = mce + (size_t)b * P;
    int npos = (int)rowacc[(size_t)b * 16];
    int k = NEGPOS * npos;
    if (k > P - 1) k = P - 1;
    if (k <= 0) return;

    const int tid  = threadIdx.x;
    const int wv   = tid >> 6;
    const int lane = tid & 63;

    float r[MINE_CH];                    // register-resident mce row slice
#pragma unroll
    for (int i = 0; i < MINE_CH; ++i) {
        const int p = i * MINE_T + tid;
        r[i] = (p < P) ? row[p] : 0.0f;
    }

    __shared__ unsigned hist[MINE_W][257];
    __shared__ unsigned binc[256];
    __shared__ unsigned s_prefix;
    __shared__ int      s_rem;

    unsigned prefix = 0u;
    int rem = k;
    for (int shift = 24; shift >= 0; shift -= 8) {
        for (int i = tid; i < MINE_W * 257; i += MINE_T) (&hist[0][0])[i] = 0u;
        __syncthreads();
        const unsigned himask = (shift == 24) ? 0u : (0xFFFFFFFFu << (shift + 8));
#pragma unroll
        for (int i = 0; i < MINE_CH; ++i) {
            unsigned bits = __float_as_uint(r[i]);
            if ((bits & himask) == prefix)
                atomicAdd(&hist[wv][(bits >> shift) & 0xFFu], 1u);
        }
        __syncthreads();
        if (tid < 256) {                 // fold the 16 wave-private copies
            unsigned c = 0;
#pragma unroll
            for (int h = 0; h < MINE_W; ++h) c += hist[h][tid];
            binc[tid] = c;
        }
        __syncthreads();
        if (tid < 64) {                  // wave-parallel descending bin scan
            const int bb0 = 255 - 4 * tid;
            unsigned c0 = binc[bb0], c1 = binc[bb0 - 1],
                     c2 = binc[bb0 - 2], c3 = binc[bb0 - 3];
            unsigned t4 = c0 + c1 + c2 + c3;
            unsigned incl = t4;
#pragma unroll
            for (int d = 1; d < 64; d <<= 1) {
                unsigned v = __shfl_up(incl, d, 64);
                if (tid >= d) incl += v;
            }
            const unsigned excl = incl - t4;   // count in bins above my group
            if ((int)excl < rem && rem <= (int)incl) {   // exactly one lane
                unsigned cum = excl;
                int bin, nrem;
                if ((int)(cum + c0) >= rem)      { bin = bb0;     nrem = rem - (int)cum; }
                else { cum += c0;
                if ((int)(cum + c1) >= rem)      { bin = bb0 - 1; nrem = rem - (int)cum; }
                else { cum += c1;
                if ((int)(cum + c2) >= rem)      { bin = bb0 - 2; nrem = rem - (int)cum; }
                else { cum += c2;                  bin = bb0 - 3; nrem = rem - (int)cum; } } }
                s_prefix = prefix | ((unsigned)bin << shift);
                s_rem    = nrem;
            }
        }
        __syncthreads();
        prefix = s_prefix;
        rem    = s_rem;
    }

    const float vk = __uint_as_float(prefix);
    float s = 0.f; int cnt = 0;
#pragma unroll
    for (int i = 0; i < MINE_CH; ++i) {
        float v = r[i];
        if (__float_as_uint(v) > prefix) { s += v; ++cnt; }
    }
#pragma unroll
    for (int d = 32; d > 0; d >>= 1) {
        s   += __shfl_down(s, d, 64);
        cnt += __shfl_down(cnt, d, 64);
    }
    __shared__ float s_ws[MINE_W];
    __shared__ int   s_wc[MINE_W];
    if (lane == 0) { s_ws[wv] = s; s_wc[wv] = cnt; }
    __syncthreads();
    if (tid == 0) {
        float st = 0.f; int ct = 0;
        for (int w = 0; w < MINE_W; ++w) { st += s_ws[w]; ct += s_wc[w]; }
        atomicAdd(g_neg, st + (float)(k - ct) * vk);
    }
}

// ---------------------------------------------------------------------------
// Kernel D: final combine + divide by N. One wave.
// ---------------------------------------------------------------------------
__global__ __launch_bounds__(64)
void finish_kernel(const float* __restrict__ rowacc,
                   const float* __restrict__ g_neg,
                   float* __restrict__ out, int B) {
    const int lane = threadIdx.x;
    float npos = 0.f, sl = 0.f, cec = 0.f, ceo = 0.f;
    for (int b = lane; b < B; b += 64) {
        float4 v = *(const float4*)(rowacc + (size_t)b * 16);
        npos += v.x; sl += v.y; cec += v.z; ceo += v.w;
    }
#pragma unroll
    for (int d = 32; d > 0; d >>= 1) {
        npos += __shfl_down(npos, d, 64);
        sl   += __shfl_down(sl,   d, 64);
        cec  += __shfl_down(cec,  d, 64);
        ceo  += __shfl_down(ceo,  d, 64);
    }
    if (lane == 0) {
        float neg = *g_neg;
        out[0] = sl / npos;
        out[1] = (cec + neg) / npos;
        out[2] = (ceo + neg) / npos;
    }
}

extern "C" void kernel_launch(void* const* d_in, const int* in_sizes, int n_in,
                              void* d_out, int out_size, void* d_ws, size_t ws_size,
                              hipStream_t stream) {
    const float* loc     = (const float*)d_in[0];
    const float* conf    = (const float*)d_in[1];
    const float* obj     = (const float*)d_in[2];
    const float* priors  = (const float*)d_in[3];
    const float* targets = (const float*)d_in[4];

    const int P = in_sizes[3] / 4;
    const int B = in_sizes[0] / (4 * P);
    const int C = in_sizes[1] / (B * P);
    const int O = in_sizes[4] / (5 * B);

    char* ws = (char*)d_ws;
    size_t off = 0;
    float* g_neg = (float*)(ws + off);             off += 64;
    float* rowacc = (float*)(ws + off);            off += (size_t)B * 16 * sizeof(float);
    unsigned long long* g_bp = (unsigned long long*)(ws + off);
    off += (size_t)B * O * sizeof(unsigned long long);
    const size_t zero_bytes = off;
    off = (off + 127) & ~(size_t)127;
    unsigned char* code = (unsigned char*)(ws + off); off += (size_t)B * P;
    off = (off + 127) & ~(size_t)127;
    float* mce = (float*)(ws + off);               off += (size_t)B * P * sizeof(float);

    hipMemsetAsync(d_ws, 0, zero_bytes, stream);

    const int chunks = (P + A1_T * NPRI - 1) / (A1_T * NPRI);
    match_kernel<<<B * chunks, A1_T, 0, stream>>>(priors, targets, code, g_bp,
                                                  B, P, O, chunks);
    force_kernel<<<B, 64, 0, stream>>>(g_bp, code, B, P, O);
    dim3 ce_grid((P + 255) / 256, B);
    ce_pos_kernel<<<ce_grid, 256, 0, stream>>>(loc, conf, obj, priors, targets,
                                               code, mce, rowacc, B, P, C, O);
    mine_kernel<<<B, MINE_T, 0, stream>>>(mce, rowacc, g_neg, P);
    finish_kernel<<<1, 64, 0, stream>>>(rowacc, g_neg, (float*)d_out, B);
}